// Round 11
// baseline (230.427 us; speedup 1.0000x reference)
//
#include <hip/hip_runtime.h>
#include <hip/hip_bf16.h>
#include <math.h>

// Problem dims (fixed by reference)
#define BB 64
#define SS 200
#define TT 32
#define VV 50000
#define EE 128
#define CC 128
#define HH 100
#define G3 300           // 3*H
#define OUTD 104
#define NTREE (BB*SS)    // 12800

typedef __attribute__((ext_vector_type(4))) float f32x4;
typedef _Float16 f16x8 __attribute__((ext_vector_type(8)));

#define L2E  1.4426950408889634f
#define NL2E (-1.4426950408889634f)
#define TL2E 2.8853900817779268f

// LDS-only barrier: waits ds-ops (lgkmcnt) but does NOT drain vmcnt, so in-flight
// global prefetch loads stay outstanding across the barrier (waited at use).
#define BAR() asm volatile("s_waitcnt lgkmcnt(0)\n\ts_barrier" ::: "memory")

// Workspace byte offsets
//   wl   @ 0      : 32768 B   (k12 W_lin fragment image, fp16)
//   k2b  @ 32768  : 163840 B  (k12 W_ih fragment image, fp16)
//   gx   @ 196608 : 30720000 B (fp32, PRESCALED: r/z = NL2E*(x+bih+bhh), n = TL2E*(x+bih))
//   pool @ 0      : 51200 B   -- aliases wl/k2b; k3 writes it AFTER k12 read them.
// (thi and emb16 are GONE: k12 fuses k1+k2, keeping tree vectors in LDS.)

// ---------------- K0: weight-fragment images only (11 blocks, idempotent)
__global__ __launch_bounds__(256) void k0_prep(const float* __restrict__ w_lin,
                                               const float* __restrict__ w_ih_f,
                                               const float* __restrict__ w_ih_b,
                                               _Float16* __restrict__ wl,
                                               _Float16* __restrict__ k2b) {
    const int tid  = threadIdx.x;
    const int wave = tid >> 6;
    const int lane = tid & 63;
    const int r = lane & 15;
    const int q = lane >> 4;
    if (blockIdx.x == 0) {
        // wl image: wave w, lane(r,q), nt, kt -> W_lin[n=w*32+nt*16+r][k=kt*32+q*8 ..+8]
#pragma unroll
        for (int nt = 0; nt < 2; ++nt)
#pragma unroll
            for (int kt = 0; kt < 4; ++kt) {
                const int n = wave * 32 + nt * 16 + r;
                const float* src = w_lin + (long)n * EE + kt * 32 + q * 8;
                f16x8 f;
#pragma unroll
                for (int e = 0; e < 8; ++e) f[e] = (_Float16)src[e];
                *(f16x8*)&wl[(size_t)((((wave * 2 + nt) * 4 + kt) * 64) + lane) * 8] = f;
            }
    } else {
        // k2b image: nb, wave w, lane(r,q), kt -> W_ih[padded n = nb*64+w*16+r][k=kt*32+q*8]
        const int nb = blockIdx.x - 1;           // 0..9
        const int n = nb * 64 + wave * 16 + r;
        const int dir = (n >= 320) ? 1 : 0;
        const int j = n - dir * 320;
        const int jj = (j < G3) ? j : 0;         // pad rows clamped (results discarded)
        const float* w = dir ? w_ih_b : w_ih_f;
#pragma unroll
        for (int kt = 0; kt < 4; ++kt) {
            const float* src = w + (long)jj * EE + kt * 32 + q * 8;
            f16x8 f;
#pragma unroll
            for (int e = 0; e < 8; ++e) f[e] = (_Float16)src[e];
            *(f16x8*)&k2b[(size_t)((((nb * 4 + wave) * 4 + kt) * 64) + lane) * 8] = f;
        }
    }
}

// ---------------- K12 (fused k1+k2): 16 trees/block, 800 blocks.
// Phase 1 (8 chunks of 2 trees): fp32 emb gather+cvt -> MFMA vs W_lin -> bias ->
// tree-sum+maxpool -> thi row into LDS (no global thi).
// Phase 2: thi_sh [16x128] is exactly one M=16 MFMA tile; multiply by the k2b
// W_ih image (10 n-groups/wave region) and write PRESCALED gx directly.
// Eliminates: thi HBM roundtrip (3.3MB w + ~16MB r), k2's A-staging, one launch.
#define TPB 16                   // trees per block
#define AROWS 64                 // nodes per chunk (2 trees)
#define LDA 136                  // fp16/row: 128 + 8 pad
#define LDC 132                  // fp32/row: 128 + 4 pad

__global__ __launch_bounds__(256, 4) void k12_fused(const int* __restrict__ tok,
                                                    const float* __restrict__ emb,
                                                    const _Float16* __restrict__ wl,
                                                    const float* __restrict__ b_lin,
                                                    const _Float16* __restrict__ k2b,
                                                    const float* __restrict__ b_ih_f,
                                                    const float* __restrict__ b_ih_b,
                                                    const float* __restrict__ b_hh_f,
                                                    const float* __restrict__ b_hh_b,
                                                    float* __restrict__ gx) {
    __shared__ __align__(16) char U_sh[AROWS * LDC * 4];   // 33792 B union (A over C)
    _Float16* A_sh = (_Float16*)U_sh;                      // 64 x LDA fp16 image
    float*    C_sh = (float*)U_sh;                         // 64 x LDC f32 image
    __shared__ __align__(16) _Float16 thi_sh[TPB][LDA];    // 4352 B
    __shared__ int tok_sh[AROWS];                          // 256 B   (total ~38.4 KB)

    const int tid  = threadIdx.x;
    const int wave = tid >> 6;
    const int lane = tid & 63;
    const int r = lane & 15;
    const int q = lane >> 4;

    const int T0 = blockIdx.x * TPB;

    // ---- W_lin B fragments: 8 coalesced 16B loads from the prebuilt image
    f16x8 bfrag[2][4];
    float bias[2];
#pragma unroll
    for (int nt = 0; nt < 2; ++nt) {
        bias[nt] = b_lin[wave * 32 + nt * 16 + r];
#pragma unroll
        for (int kt = 0; kt < 4; ++kt)
            bfrag[nt][kt] = *(const f16x8*)&wl[(size_t)((((wave * 2 + nt) * 4 + kt) * 64) + lane) * 8];
    }

    // ================= Phase 1: 8 chunks x (gather -> GEMM -> tree-sum) =========
    for (int c = 0; c < 8; ++c) {
        if (tid < AROWS) tok_sh[tid] = tok[(T0 + 2 * c) * TT + tid];
        __syncthreads();   // tok ready; prev chunk's C_sh reads done -> A_sh writable

        // gather fp32 embeddings -> cvt -> A_sh (one cvt per element)
#pragma unroll
        for (int i = 0; i < 8; ++i) {
            const int idx = tid + i * 256;   // 0..2047
            const int row = idx >> 5;        // 64 rows, 32 float4 each
            const int p   = idx & 31;
            const float4 e = ((const float4*)(emb + (long)tok_sh[row] * EE))[p];
            _Float16* dst = &A_sh[row * LDA + p * 4];
            dst[0] = (_Float16)e.x; dst[1] = (_Float16)e.y;
            dst[2] = (_Float16)e.z; dst[3] = (_Float16)e.w;
        }
        __syncthreads();

        f32x4 acc[4][2];
#pragma unroll
        for (int mt = 0; mt < 4; ++mt)
#pragma unroll
            for (int nt = 0; nt < 2; ++nt) acc[mt][nt] = (f32x4)(0.f);

#pragma unroll
        for (int mt = 0; mt < 4; ++mt) {
            const int m = mt * 16 + r;
            f16x8 afrag[4];
#pragma unroll
            for (int kt = 0; kt < 4; ++kt)
                afrag[kt] = *(const f16x8*)&A_sh[m * LDA + kt * 32 + q * 8];
#pragma unroll
            for (int nt = 0; nt < 2; ++nt)
#pragma unroll
                for (int kt = 0; kt < 4; ++kt)
                    acc[mt][nt] = __builtin_amdgcn_mfma_f32_16x16x32_f16(
                        afrag[kt], bfrag[nt][kt], acc[mt][nt], 0, 0, 0);
        }
        __syncthreads();   // A_sh reads done -> C_sh (union) writable

#pragma unroll
        for (int mt = 0; mt < 4; ++mt)
#pragma unroll
            for (int nt = 0; nt < 2; ++nt) {
                const int col = wave * 32 + nt * 16 + r;
#pragma unroll
                for (int reg = 0; reg < 4; ++reg) {
                    const int row = mt * 16 + q * 4 + reg;
                    C_sh[row * LDC + col] = acc[mt][nt][reg] + bias[nt];
                }
            }
        __syncthreads();

        // tree-sum + maxpool (descending index = topological order)
        {
            const int t = tid >> 7;          // 0..1 (tree within chunk)
            const int j = tid & 127;
            const float* base = &C_sh[(t * TT) * LDC + j];
            float v[TT];
#pragma unroll
            for (int n = 0; n < TT; ++n) v[n] = base[n * LDC];
            float mx = -1e30f;
#pragma unroll
            for (int n = TT - 1; n >= 1; --n) {
                mx = fmaxf(mx, v[n]);
                v[(n - 1) >> 1] += v[n];
            }
            mx = fmaxf(mx, v[0]);
            thi_sh[2 * c + t][j] = (_Float16)mx;   // fp32 sums, one fp16 round
        }
        // loop-top barrier protects C_sh/tok_sh reuse
    }
    __syncthreads();   // thi_sh complete

    // ================= Phase 2: gx[T0..T0+15][600] = thi @ W_ih^T (prescaled) ====
    // A-frags: one M=16 tile from LDS (row stride 136 fp16 = 68 words -> 2-way
    // bank alias = free). Constant across all 10 n-groups.
    f16x8 a4[4];
#pragma unroll
    for (int kt = 0; kt < 4; ++kt)
        a4[kt] = *(const f16x8*)&thi_sh[r][kt * 32 + q * 8];

#pragma unroll
    for (int nb = 0; nb < 10; ++nb) {
        f16x8 bh[4];
#pragma unroll
        for (int kt = 0; kt < 4; ++kt)
            bh[kt] = *(const f16x8*)&k2b[(size_t)((((nb * 4 + wave) * 4 + kt) * 64) + lane) * 8];
        f32x4 acc = (f32x4)(0.f);
#pragma unroll
        for (int kt = 0; kt < 4; ++kt)
            acc = __builtin_amdgcn_mfma_f32_16x16x32_f16(a4[kt], bh[kt], acc, 0, 0, 0);

        const int ng  = nb * 64 + wave * 16 + r;
        const int dir = (ng >= 320) ? 1 : 0;
        const int j   = ng - dir * 320;
        const bool valid = (j < G3);
        const float* b_ih = dir ? b_ih_b : b_ih_f;
        const float* b_hh = dir ? b_hh_b : b_hh_f;
        const float bias2 = valid ? b_ih[j] : 0.f;
        const float bh2   = (valid && j < 2 * HH) ? b_hh[j] : 0.f;
        const float sc    = (j < 2 * HH) ? NL2E : TL2E;
        float* gxd = gx + (long)dir * NTREE * G3;
        if (valid) {
#pragma unroll
            for (int reg = 0; reg < 4; ++reg) {
                const int m = T0 + q * 4 + reg;
                gxd[(long)m * G3 + j] = sc * (acc[reg] + bias2 + bh2);
            }
        }
    }
}

// ---------------- K3 v13 (FROZEN at structural floor, 87.5-88.5 us measured):
// v7 structure (4-wave chain, 4-deep RAW named prefetch, one lgkm-barrier/step)
// + prescaled gx/W_hh. Nine structural variants bracket this at >=88 us.
__global__ __launch_bounds__(256, 1) void k3_gru(const float* __restrict__ gx,
                                                 const float* __restrict__ w_hh_f,
                                                 const float* __restrict__ b_hh_f,
                                                 const float* __restrict__ w_hh_b,
                                                 const float* __restrict__ b_hh_b,
                                                 float* __restrict__ pool) {
    const int bid = blockIdx.x;   // 0..127
    const int dir = bid & 1;
    const int b = bid >> 1;
    const float* w_hh = dir ? w_hh_b : w_hh_f;
    const float* b_hh = dir ? b_hh_b : b_hh_f;

    __shared__ __align__(16) _Float16 h_sh[2][128];

    const int tid  = threadIdx.x;
    const int wave = tid >> 6;
    const int lane = tid & 63;
    const int r = lane & 15;
    const int q = lane >> 4;

    // W_hh fragments, row-permuted AND prescaled: tile i, lane r -> l=i*16+r;
    // gate=l/25, ch=l-25*gate; row = gate*H + wave*25 + ch (l>=75 zero-padded);
    // gates r,z scaled by -log2(e), gate n by +2*log2(e).
    f16x8 bf[5][4];
#pragma unroll
    for (int i = 0; i < 5; ++i) {
        const int l = i * 16 + r;
        const int gate = l / 25;
        const int ch   = l - gate * 25;
        const bool nv  = (l < 75);
        const int row  = gate * HH + wave * 25 + ch;
        const float sc = (gate == 2) ? TL2E : NL2E;
#pragma unroll
        for (int kt = 0; kt < 4; ++kt) {
            f16x8 f;
#pragma unroll
            for (int e = 0; e < 8; ++e) {
                const int k = kt * 32 + q * 8 + e;
                f[e] = (_Float16)((nv && k < HH) ? sc * w_hh[row * HH + k] : 0.f);
            }
            bf[i][kt] = f;
        }
    }

    const int m = lane;
    const int c = wave * 25 + m;
    const bool act = (m < 25);
    // only the n-gate hidden bias stays in-kernel (r/z hidden biases folded in gx)
    const float bnc = act ? TL2E * b_hh[2 * HH + c] : 0.f;

    // bpermute source lanes: V1 at lane l holds gh[l] (l<64); g4 at lane r holds gh[64+r]
    const int a_z  = (25 + m) & 63;          // row 25+m
    const int a_n1 = (50 + m) & 63;          // row 50+m if < 64
    const int a_n2 = (50 + m - 64) & 63;     // row 50+m if >= 64 (from g4)
    const bool nV1 = (50 + m) < 64;

    if (tid < 128) { h_sh[0][tid] = (_Float16)0.f; h_sh[1][tid] = (_Float16)0.f; }

    const int sstep = dir ? -1 : 1;
    const int s0 = dir ? (SS - 1) : 0;
    // lane-local base pointer into this chain's gx rows (valid for act lanes)
    const float* gp = gx + (long)dir * NTREE * G3 + (long)b * SS * G3 + c;

    // 4-deep prefetch, NAMED buffers, RAW loads only
    float pxr[4], pxz[4], pxn[4];
    if (act) {
#pragma unroll
        for (int j = 0; j < 4; ++j) {
            const long off = (long)(s0 + j * sstep) * G3;
            pxr[j] = gp[off]; pxz[j] = gp[off + HH]; pxn[j] = gp[off + 2 * HH];
        }
    }
    float hj = 0.f, hmax = -1e30f;
    __syncthreads();

    int s = s0;
    for (int t = 0; t < SS; t += 4) {
#pragma unroll
        for (int j = 0; j < 4; ++j) {
            const int p = j & 1;             // (t+j)&1, t multiple of 4

            f16x8 a[4];
#pragma unroll
            for (int kt = 0; kt < 4; ++kt)
                a[kt] = *(const f16x8*)&h_sh[p][kt * 32 + q * 8];

            // split-K: two parallel depth-2 chains per tile
            f32x4 accA[5], accB[5];
#pragma unroll
            for (int i = 0; i < 5; ++i) {
                accA[i] = (f32x4)(0.f);
                accB[i] = (f32x4)(0.f);
                accA[i] = __builtin_amdgcn_mfma_f32_16x16x32_f16(a[0], bf[i][0], accA[i], 0, 0, 0);
                accB[i] = __builtin_amdgcn_mfma_f32_16x16x32_f16(a[2], bf[i][2], accB[i], 0, 0, 0);
                accA[i] = __builtin_amdgcn_mfma_f32_16x16x32_f16(a[1], bf[i][1], accA[i], 0, 0, 0);
                accB[i] = __builtin_amdgcn_mfma_f32_16x16x32_f16(a[3], bf[i][3], accB[i], 0, 0, 0);
            }
            const float g0 = accA[0][0] + accB[0][0];
            const float g1 = accA[1][0] + accB[1][0];
            const float g2 = accA[2][0] + accB[2][0];
            const float g3 = accA[3][0] + accB[3][0];
            const float g4 = accA[4][0] + accB[4][0];
            // V1 at lane l = gh[row l] (rows 0..63); g4 at lane r = gh[64+r] (rows 64..74)
            float V1 = g0;
            V1 = (q == 1) ? g1 : V1;
            V1 = (q == 2) ? g2 : V1;
            V1 = (q == 3) ? g3 : V1;
            const float ghr = V1;                    // row m == own lane
            const float ghz = __shfl(V1, a_z);       // row 25+m
            const float vnA = __shfl(V1, a_n1);
            const float vnB = __shfl(g4, a_n2);
            const float ghn = nV1 ? vnA : vnB;       // row 50+m

            if (act) {
                // all exp2 args prebuilt: rg = sigmoid, via rcp(1+exp2(·))
                const float rg = __builtin_amdgcn_rcpf(1.f + __builtin_amdgcn_exp2f(pxr[j] + ghr));
                const float zg = __builtin_amdgcn_rcpf(1.f + __builtin_amdgcn_exp2f(pxz[j] + ghz));
                const float t1 = ghn + bnc;                          // parallel with rg
                const float an = __builtin_fmaf(rg, t1, pxn[j]);
                const float u  = __builtin_amdgcn_rcpf(1.f + __builtin_amdgcn_exp2f(an));
                const float n  = __builtin_fmaf(-2.f, u, 1.f);       // tanh
                hj = __builtin_fmaf(zg, hj - n, n);                  // (1-z)n + z h
                h_sh[1 - p][c] = (_Float16)hj;                       // write ASAP
                hmax = fmaxf(hmax, hj);
                // refill slot j for step t+j+4: RAW loads, no dependent ops
                if (t + j + 4 < SS) {
                    const long off = (long)(s + (j + 4) * sstep) * G3;
                    pxr[j] = gp[off]; pxz[j] = gp[off + HH]; pxn[j] = gp[off + 2 * HH];
                }
            }
            BAR();
        }
        s += 4 * sstep;
    }
    if (act) pool[(long)b * (2 * HH) + dir * HH + c] = hmax;
}

// ---------------- K4: out[b][o] = fc_b[o] + pool[b,:] . fc_w[o,:]
__global__ __launch_bounds__(256) void k4_fc(const float* __restrict__ pool,
                                             const float* __restrict__ fc_w,
                                             const float* __restrict__ fc_b,
                                             float* __restrict__ out) {
    const int b = blockIdx.x;
    __shared__ __align__(16) float p_sh[2 * HH];
    const int t = threadIdx.x;
    if (t < 2 * HH) p_sh[t] = pool[(long)b * (2 * HH) + t];
    __syncthreads();
    if (t < OUTD) {
        const float4* wr4 = (const float4*)(fc_w + (long)t * (2 * HH));
        const float4* p4 = (const float4*)p_sh;
        float a0 = 0.f, a1 = 0.f;
#pragma unroll
        for (int k = 0; k < 50; k += 2) {
            float4 w0 = wr4[k],   p0 = p4[k];
            float4 w1 = wr4[k+1], p1 = p4[k+1];
            a0 += w0.x*p0.x + w0.y*p0.y + w0.z*p0.z + w0.w*p0.w;
            a1 += w1.x*p1.x + w1.y*p1.y + w1.z*p1.z + w1.w*p1.w;
        }
        out[(long)b * OUTD + t] = fc_b[t] + a0 + a1;
    }
}

extern "C" void kernel_launch(void* const* d_in, const int* in_sizes, int n_in,
                              void* d_out, int out_size, void* d_ws, size_t ws_size,
                              hipStream_t stream) {
    const int*   tok    = (const int*)d_in[0];
    const float* emb    = (const float*)d_in[4];
    const float* w_lin  = (const float*)d_in[5];
    const float* b_lin  = (const float*)d_in[6];
    const float* w_ih_f = (const float*)d_in[7];
    const float* w_hh_f = (const float*)d_in[8];
    const float* b_ih_f = (const float*)d_in[9];
    const float* b_hh_f = (const float*)d_in[10];
    const float* w_ih_b = (const float*)d_in[11];
    const float* w_hh_b = (const float*)d_in[12];
    const float* b_ih_b = (const float*)d_in[13];
    const float* b_hh_b = (const float*)d_in[14];
    const float* fc_w   = (const float*)d_in[15];
    const float* fc_b   = (const float*)d_in[16];

    char* wsb = (char*)d_ws;
    _Float16* wl   = (_Float16*)(wsb);            // 32768 B
    _Float16* k2b  = (_Float16*)(wsb + 32768);    // 163840 B
    float*    gx   = (float*)(wsb + 196608);      // 30720000 B (ends 30.9 MB)
    float*    pool = (float*)(wsb);               // aliases wl/k2b: k3 runs after k12
    float*    out  = (float*)d_out;

    k0_prep  <<<11, 256, 0, stream>>>(w_lin, w_ih_f, w_ih_b, wl, k2b);
    k12_fused<<<NTREE / TPB, 256, 0, stream>>>(tok, emb, wl, b_lin, k2b,
                                               b_ih_f, b_ih_b, b_hh_f, b_hh_b, gx);
    k3_gru   <<<2 * BB, 256, 0, stream>>>(gx, w_hh_f, b_hh_f, w_hh_b, b_hh_b, pool);
    k4_fc    <<<BB, 256, 0, stream>>>(pool, fc_w, fc_b, out);
}